// Round 1
// baseline (83.796 us; speedup 1.0000x reference)
//
#include <hip/hip_runtime.h>
#include <math.h>

// MMD loss, algebraically reduced:
//   sum(L2) = 2n*S - 2*||colsum||^2   (S = sum of squared norms, n = 2B)
//   loss needs kernel_val at only 4B shifted-diagonal entries.
//
// B=4096, D=256, n=8192, KERNEL_MUL=2, KERNEL_NUM=5.

#define B_SZ 4096
#define D_SZ 256
#define ABLK 256  // blocks in reduce kernel

// ws layout (floats):
//   [0..4]                     : inv_bw[5]  (written by bw_kernel)
//   [8 .. 8+ABLK)              : partial S per block
//   [512 .. 512+ABLK*256)      : partial colsum [block][col]
#define WS_S    8
#define WS_PART 512

__device__ __forceinline__ float dot4(float4 a, float4 b) {
    return a.x * b.x + a.y * b.y + a.z * b.z + a.w * b.w;
}

// ---------------- Kernel 1: partial colsums + partial sum-of-squares -------
__global__ __launch_bounds__(256) void reduce_kernel(const float* __restrict__ src,
                                                     const float* __restrict__ tgt,
                                                     float* __restrict__ ws) {
    const int tid = threadIdx.x;
    const int gid = blockIdx.x * 256 + tid;
    const int cg  = tid & 63;  // column group (float4); invariant across iters

    const float4* S4 = (const float4*)src;
    const float4* T4 = (const float4*)tgt;

    float4 cs = make_float4(0.f, 0.f, 0.f, 0.f);
    float  sq = 0.f;
    // total float4 elements = 8192 rows * 64 = 524288; grid threads = 65536
#pragma unroll
    for (int it = 0; it < 8; ++it) {
        int f   = gid + it * 65536;
        int row = f >> 6;
        float4 v = (row < B_SZ) ? S4[f] : T4[f - B_SZ * 64];
        cs.x += v.x; cs.y += v.y; cs.z += v.z; cs.w += v.w;
        sq += v.x * v.x + v.y * v.y + v.z * v.z + v.w * v.w;
    }

    // reduce sq across the wave
    for (int o = 32; o; o >>= 1) sq += __shfl_xor(sq, o, 64);

    __shared__ float4 lcs[4][64];
    __shared__ float  lsq[4];
    const int sub = tid >> 6;
    lcs[sub][cg] = cs;
    if ((tid & 63) == 0) lsq[sub] = sq;
    __syncthreads();

    if (sub == 0) {
        float4 a = lcs[0][cg], b = lcs[1][cg], c = lcs[2][cg], d = lcs[3][cg];
        float4 t = make_float4(a.x + b.x + c.x + d.x, a.y + b.y + c.y + d.y,
                               a.z + b.z + c.z + d.z, a.w + b.w + c.w + d.w);
        ((float4*)(ws + WS_PART + blockIdx.x * 256))[cg] = t;
    }
    if (tid == 0) ws[WS_S + blockIdx.x] = lsq[0] + lsq[1] + lsq[2] + lsq[3];
}

// ---------------- Kernel 2: bandwidth from partials; zero d_out ------------
__global__ __launch_bounds__(256) void bw_kernel(float* __restrict__ ws,
                                                 float* __restrict__ out) {
    const int tid = threadIdx.x;
    const float* part = ws + WS_PART;
    float s = 0.f;
#pragma unroll 8
    for (int b = 0; b < ABLK; ++b) s += part[b * 256 + tid];
    float s2 = s * s;
    float Sp = ws[WS_S + tid];  // ABLK == 256 == blockDim

    for (int o = 32; o; o >>= 1) {
        s2 += __shfl_xor(s2, o, 64);
        Sp += __shfl_xor(Sp, o, 64);
    }
    __shared__ float l2[4], lS[4];
    if ((tid & 63) == 0) { l2[tid >> 6] = s2; lS[tid >> 6] = Sp; }
    __syncthreads();

    if (tid == 0) {
        double norm2 = (double)l2[0] + l2[1] + l2[2] + l2[3];
        double S     = (double)lS[0] + lS[1] + lS[2] + lS[3];
        double n     = 2.0 * B_SZ;
        double sumL2 = 2.0 * n * S - 2.0 * norm2;
        double bw    = sumL2 / (n * n - n);
        bw = bw / 4.0;  // KERNEL_MUL ** (KERNEL_NUM // 2) = 2^2
#pragma unroll
        for (int k = 0; k < 5; ++k) ws[k] = (float)(1.0 / (bw * (double)(1 << k)));
        out[0] = 0.f;
    }
}

// ---------------- Kernel 3: shifted-diagonal kernel values + loss ----------
__global__ __launch_bounds__(256) void loss_kernel(const float* __restrict__ src,
                                                   const float* __restrict__ tgt,
                                                   const float* __restrict__ ws,
                                                   float* __restrict__ out) {
    const int tid  = threadIdx.x;
    const int w    = tid >> 6;
    const int lane = tid & 63;

    const float ib0 = ws[0], ib1 = ws[1], ib2 = ws[2], ib3 = ws[3], ib4 = ws[4];

    const float4* S4 = (const float4*)src;
    const float4* T4 = (const float4*)tgt;

    float wacc = 0.f;
#pragma unroll
    for (int q = 0; q < 4; ++q) {
        const int p = blockIdx.x * 16 + w * 4 + q;
        const int i = p;
        const int j = (p + 1) & (B_SZ - 1);

        float4 a = S4[i * 64 + lane];
        float4 b = S4[j * 64 + lane];
        float4 c = T4[i * 64 + lane];
        float4 d = T4[j * 64 + lane];

        float sqa = dot4(a, a), sqb = dot4(b, b), sqc = dot4(c, c), sqd = dot4(d, d);
        float ss = dot4(a, b), tt = dot4(c, d), st = dot4(a, d), ts = dot4(b, c);

        for (int o = 32; o; o >>= 1) {
            sqa += __shfl_xor(sqa, o, 64);
            sqb += __shfl_xor(sqb, o, 64);
            sqc += __shfl_xor(sqc, o, 64);
            sqd += __shfl_xor(sqd, o, 64);
            ss  += __shfl_xor(ss,  o, 64);
            tt  += __shfl_xor(tt,  o, 64);
            st  += __shfl_xor(st,  o, 64);
            ts  += __shfl_xor(ts,  o, 64);
        }

        if (lane == 0) {
            // quadratic-expansion L2, matching the reference's formula
            float L2ss = sqa + sqb - 2.f * ss;
            float L2tt = sqc + sqd - 2.f * tt;
            float L2st = sqa + sqd - 2.f * st;
            float L2ts = sqb + sqc - 2.f * ts;
            float k = 0.f;
            k += expf(-L2ss * ib0) + expf(-L2tt * ib0) - expf(-L2st * ib0) - expf(-L2ts * ib0);
            k += expf(-L2ss * ib1) + expf(-L2tt * ib1) - expf(-L2st * ib1) - expf(-L2ts * ib1);
            k += expf(-L2ss * ib2) + expf(-L2tt * ib2) - expf(-L2st * ib2) - expf(-L2ts * ib2);
            k += expf(-L2ss * ib3) + expf(-L2tt * ib3) - expf(-L2st * ib3) - expf(-L2ts * ib3);
            k += expf(-L2ss * ib4) + expf(-L2tt * ib4) - expf(-L2st * ib4) - expf(-L2ts * ib4);
            wacc += k;
        }
    }

    __shared__ float lacc[4];
    if (lane == 0) lacc[w] = wacc;
    __syncthreads();
    if (tid == 0) {
        float t = (lacc[0] + lacc[1] + lacc[2] + lacc[3]) * (1.0f / (float)B_SZ);
        atomicAdd(out, t);
    }
}

extern "C" void kernel_launch(void* const* d_in, const int* in_sizes, int n_in,
                              void* d_out, int out_size, void* d_ws, size_t ws_size,
                              hipStream_t stream) {
    const float* src = (const float*)d_in[0];
    const float* tgt = (const float*)d_in[1];
    float* out = (float*)d_out;
    float* ws  = (float*)d_ws;

    reduce_kernel<<<ABLK, 256, 0, stream>>>(src, tgt, ws);
    bw_kernel<<<1, 256, 0, stream>>>(ws, out);
    loss_kernel<<<B_SZ / 16, 256, 0, stream>>>(src, tgt, ws, out);
}

// Round 2
// 80.729 us; speedup vs baseline: 1.0380x; 1.0380x over previous
//
#include <hip/hip_runtime.h>
#include <math.h>

// MMD loss, algebraically reduced O(n*D):
//   sum(L2) = 2n*S - 2*||colsum||^2   (S = sum of squared norms, n = 2B)
//   loss needs kernel_val at only 4B shifted-diagonal entries; the 4 L2
//   values per pair are bandwidth-independent, so K1 computes them in the
//   same pass that produces the colsum/S partials (rows read once, ~10 MB).
//
// B=4096, D=256, n=8192, KERNEL_MUL=2, KERNEL_NUM=5.

#define B_SZ 4096
#define NBLK 256

// ws layout (floats):
//   [8 .. 8+256)          : partial S per block
//   [1024 .. 1024+16384)  : L2 quads, float4 per pair {ss,tt,st,ts}
//   [32768 .. 32768+65536): colsum partials, transposed [col][block]
#define WS_SP   8
#define WS_L2   1024
#define WS_PART 32768

__device__ __forceinline__ float dot4(float4 a, float4 b) {
    return a.x * b.x + a.y * b.y + a.z * b.z + a.w * b.w;
}

// ---- K1: per-wave = 4 pairs. Loads 5 src + 5 tgt rows, produces the 4
//      pairs' L2 quads + this block's colsum/S partials. --------------------
__global__ __launch_bounds__(256) void pair_reduce_kernel(const float* __restrict__ src,
                                                          const float* __restrict__ tgt,
                                                          float* __restrict__ ws) {
    const int tid  = threadIdx.x;
    const int w    = tid >> 6;
    const int lane = tid & 63;
    const int base = blockIdx.x * 16 + w * 4;  // first pair index of this wave

    const float4* S4 = (const float4*)src;
    const float4* T4 = (const float4*)tgt;

    float4 a[5], c[5];
#pragma unroll
    for (int q = 0; q < 5; ++q) {
        const int r = (base + q) & (B_SZ - 1);  // wrap only matters for the last pair
        a[q] = S4[r * 64 + lane];
        c[q] = T4[r * 64 + lane];
    }

    // colsum over the 4 owned rows (src + tgt)
    float4 cs = make_float4(0.f, 0.f, 0.f, 0.f);
#pragma unroll
    for (int q = 0; q < 4; ++q) {
        cs.x += a[q].x + c[q].x;
        cs.y += a[q].y + c[q].y;
        cs.z += a[q].z + c[q].z;
        cs.w += a[q].w + c[q].w;
    }

    // 26 per-wave reductions: sqa[0..4], sqc[0..4], ss[0..3], tt[0..3],
    // st[0..3] (src_i . tgt_j), ts[0..3] (src_j . tgt_i)
    float red[26];
#pragma unroll
    for (int q = 0; q < 5; ++q) {
        red[q]     = dot4(a[q], a[q]);
        red[5 + q] = dot4(c[q], c[q]);
    }
#pragma unroll
    for (int q = 0; q < 4; ++q) {
        red[10 + q] = dot4(a[q], a[q + 1]);
        red[14 + q] = dot4(c[q], c[q + 1]);
        red[18 + q] = dot4(a[q], c[q + 1]);
        red[22 + q] = dot4(a[q + 1], c[q]);
    }
#pragma unroll
    for (int r = 0; r < 26; ++r) {
#pragma unroll
        for (int o = 32; o; o >>= 1) red[r] += __shfl_xor(red[r], o, 64);
    }

    // block combine: colsum + S
    __shared__ float4 lcs[4][64];
    __shared__ float  lsq[4];
    lcs[w][lane] = cs;
    if (lane == 0)
        lsq[w] = red[0] + red[1] + red[2] + red[3] + red[5] + red[6] + red[7] + red[8];
    __syncthreads();

    if (w == 0) {
        float4 x = lcs[0][lane], y = lcs[1][lane], z = lcs[2][lane], u = lcs[3][lane];
        const int b = blockIdx.x;
        // transposed store: [col][block] so the reducer reads contiguously
        ws[WS_PART + (4 * lane + 0) * NBLK + b] = x.x + y.x + z.x + u.x;
        ws[WS_PART + (4 * lane + 1) * NBLK + b] = x.y + y.y + z.y + u.y;
        ws[WS_PART + (4 * lane + 2) * NBLK + b] = x.z + y.z + z.z + u.z;
        ws[WS_PART + (4 * lane + 3) * NBLK + b] = x.w + y.w + z.w + u.w;
        if (lane == 0) ws[WS_SP + b] = lsq[0] + lsq[1] + lsq[2] + lsq[3];
    }

    // pair L2 quads (quadratic expansion, matching reference numerics)
    if (lane == 0) {
#pragma unroll
        for (int q = 0; q < 4; ++q) {
            float4 o;
            o.x = red[q]     + red[1 + q] - 2.f * red[10 + q];  // src_i  vs src_j
            o.y = red[5 + q] + red[6 + q] - 2.f * red[14 + q];  // tgt_i  vs tgt_j
            o.z = red[q]     + red[6 + q] - 2.f * red[18 + q];  // src_i  vs tgt_j
            o.w = red[1 + q] + red[5 + q] - 2.f * red[22 + q];  // src_j  vs tgt_i
            ((float4*)(ws + WS_L2))[base + q] = o;
        }
    }
}

// ---- K2 (single block): bandwidth from partials, then all 81920 exps and
//      the final loss, written straight to out[0]. -------------------------
__global__ __launch_bounds__(256) void finish_kernel(float* __restrict__ ws,
                                                     float* __restrict__ out) {
    const int tid = threadIdx.x;
    const int w   = tid >> 6;

    // colsum[tid] = sum over blocks (row tid of the transposed partials)
    const float4* p4 = (const float4*)(ws + WS_PART);
    float s = 0.f;
#pragma unroll 8
    for (int i = 0; i < 64; ++i) {
        float4 v = p4[tid * 64 + i];
        s += v.x + v.y + v.z + v.w;
    }
    float s2 = s * s;
    float Sp = ws[WS_SP + tid];  // 256 partials == blockDim
#pragma unroll
    for (int o = 32; o; o >>= 1) {
        s2 += __shfl_xor(s2, o, 64);
        Sp += __shfl_xor(Sp, o, 64);
    }

    __shared__ float l2[4], lS[4];
    __shared__ float sh_ib[5];
    if ((tid & 63) == 0) { l2[w] = s2; lS[w] = Sp; }
    __syncthreads();

    if (tid == 0) {
        double norm2 = (double)l2[0] + l2[1] + l2[2] + l2[3];
        double S     = (double)lS[0] + lS[1] + lS[2] + lS[3];
        double n     = 2.0 * B_SZ;
        double bw    = (2.0 * n * S - 2.0 * norm2) / (n * n - n) / 4.0;
#pragma unroll
        for (int k = 0; k < 5; ++k) sh_ib[k] = (float)(1.0 / (bw * (double)(1 << k)));
    }
    __syncthreads();

    const float ib0 = sh_ib[0], ib1 = sh_ib[1], ib2 = sh_ib[2],
                ib3 = sh_ib[3], ib4 = sh_ib[4];

    const float4* L4 = (const float4*)(ws + WS_L2);
    float acc = 0.f;
#pragma unroll
    for (int r = 0; r < 16; ++r) {
        float4 q = L4[tid + r * 256];
        acc += expf(-q.x * ib0) + expf(-q.y * ib0) - expf(-q.z * ib0) - expf(-q.w * ib0);
        acc += expf(-q.x * ib1) + expf(-q.y * ib1) - expf(-q.z * ib1) - expf(-q.w * ib1);
        acc += expf(-q.x * ib2) + expf(-q.y * ib2) - expf(-q.z * ib2) - expf(-q.w * ib2);
        acc += expf(-q.x * ib3) + expf(-q.y * ib3) - expf(-q.z * ib3) - expf(-q.w * ib3);
        acc += expf(-q.x * ib4) + expf(-q.y * ib4) - expf(-q.z * ib4) - expf(-q.w * ib4);
    }
#pragma unroll
    for (int o = 32; o; o >>= 1) acc += __shfl_xor(acc, o, 64);

    __shared__ float la[4];
    if ((tid & 63) == 0) la[w] = acc;
    __syncthreads();
    if (tid == 0) out[0] = (la[0] + la[1] + la[2] + la[3]) * (1.0f / (float)B_SZ);
}

extern "C" void kernel_launch(void* const* d_in, const int* in_sizes, int n_in,
                              void* d_out, int out_size, void* d_ws, size_t ws_size,
                              hipStream_t stream) {
    const float* src = (const float*)d_in[0];
    const float* tgt = (const float*)d_in[1];
    float* out = (float*)d_out;
    float* ws  = (float*)d_ws;

    pair_reduce_kernel<<<NBLK, 256, 0, stream>>>(src, tgt, ws);
    finish_kernel<<<1, 256, 0, stream>>>(ws, out);
}